// Round 1
// baseline (230.849 us; speedup 1.0000x reference)
//
#include <hip/hip_runtime.h>

// Problem constants (match reference)
#define B_DIM   64
#define M_DIM   128
#define F_HALF  32      // F1 == F2 == 32
#define K_DIM   64      // F1 + F2
#define NFILT   32      // FILTERS

// out[b,i,f] = sum_k ( sum_j adj[b,i,j] * x[b,i,j,k] ) * W[k,f] + deg[b,i]*bias[f]
// One block per (b,i) row. 256 threads = 4 waves.
__global__ __launch_bounds__(256)
void gconv_kernel(const float* __restrict__ sf1,
                  const float* __restrict__ sf2,
                  const float* __restrict__ adj,
                  const float* __restrict__ W,
                  const float* __restrict__ bias,
                  float* __restrict__ out)
{
    __shared__ float s_adj[M_DIM];
    __shared__ int   s_idx[M_DIM];
    __shared__ int   s_cnt;
    __shared__ float s_deg;
    __shared__ float s_acc[4][K_DIM];
    __shared__ float s_y[K_DIM];
    __shared__ float s_W[K_DIM * NFILT];   // 8 KB

    const int bid  = blockIdx.x;           // b*M + i
    const int t    = threadIdx.x;
    const int w    = t >> 6;               // wave 0..3
    const int lane = t & 63;

    if (t == 0) s_cnt = 0;

    // Preload W into LDS (2048 floats / 256 threads = 8 each, coalesced)
    #pragma unroll
    for (int r = 0; r < 8; ++r)
        s_W[r * 256 + t] = W[r * 256 + t];

    __syncthreads();

    // Phase 1: load adjacency row, compact nonzero indices
    const float* adj_row = adj + (size_t)bid * M_DIM;
    if (t < M_DIM) {
        float a = adj_row[t];
        s_adj[t] = a;
        if (a != 0.0f) {
            int p = atomicAdd(&s_cnt, 1);
            s_idx[p] = t;
        }
    }
    __syncthreads();
    const int cnt = s_cnt;

    // Phase 2: masked pooling over compacted neighbor list.
    // lane k in [0,64): k<32 -> sf1 feature k, else sf2 feature k-32.
    const size_t row_base = (size_t)bid * M_DIM * F_HALF;
    const float* base = (lane < F_HALF)
                          ? (sf1 + row_base + lane)
                          : (sf2 + row_base + (lane - F_HALF));

    float acc = 0.0f;
    for (int e = w; e < cnt; e += 16) {
        // up to 4 independent entries for this wave per iteration
        float a0 = 0.f, a1 = 0.f, a2 = 0.f, a3 = 0.f;
        float v0 = 0.f, v1 = 0.f, v2 = 0.f, v3 = 0.f;
        {
            int j = s_idx[e];
            a0 = s_adj[j];
            v0 = base[(size_t)j * F_HALF];
        }
        if (e + 4 < cnt) {
            int j = s_idx[e + 4];
            a1 = s_adj[j];
            v1 = base[(size_t)j * F_HALF];
        }
        if (e + 8 < cnt) {
            int j = s_idx[e + 8];
            a2 = s_adj[j];
            v2 = base[(size_t)j * F_HALF];
        }
        if (e + 12 < cnt) {
            int j = s_idx[e + 12];
            a3 = s_adj[j];
            v3 = base[(size_t)j * F_HALF];
        }
        acc += a0 * v0;
        acc += a1 * v1;
        acc += a2 * v2;
        acc += a3 * v3;
    }
    s_acc[w][lane] = acc;

    // degree = sum_j adj[b,i,j] (wave 1 computes it concurrently with the store)
    if (w == 1) {
        float d = s_adj[lane] + s_adj[lane + 64];
        #pragma unroll
        for (int off = 32; off; off >>= 1)
            d += __shfl_down(d, off);
        if (lane == 0) s_deg = d;
    }
    __syncthreads();

    // Cross-wave reduce into y[k]
    if (t < K_DIM)
        s_y[t] = s_acc[0][t] + s_acc[1][t] + s_acc[2][t] + s_acc[3][t];
    __syncthreads();

    // Phase 3: tiny GEMV  out[f] = deg*bias[f] + sum_k y[k]*W[k,f]
    if (t < NFILT) {
        float o = s_deg * bias[t];
        #pragma unroll
        for (int k = 0; k < K_DIM; ++k)
            o += s_y[k] * s_W[k * NFILT + t];   // s_y broadcast; s_W bank-conflict-free
        out[(size_t)bid * NFILT + t] = o;
    }
}

extern "C" void kernel_launch(void* const* d_in, const int* in_sizes, int n_in,
                              void* d_out, int out_size, void* d_ws, size_t ws_size,
                              hipStream_t stream) {
    const float* sf1  = (const float*)d_in[0];
    const float* sf2  = (const float*)d_in[1];
    const float* adj  = (const float*)d_in[2];
    const float* W    = (const float*)d_in[3];
    const float* bias = (const float*)d_in[4];
    float* out = (float*)d_out;

    gconv_kernel<<<B_DIM * M_DIM, 256, 0, stream>>>(sf1, sf2, adj, W, bias, out);
}